// Round 1
// baseline (412.179 us; speedup 1.0000x reference)
//
#include <hip/hip_runtime.h>
#include <stdint.h>

#define DMODEL 768
#define NHEADS 12
#define DK 64
#define BATCH 4
#define SEQ 2048
#define MTOK (BATCH*SEQ)   // 8192 tokens

typedef float f32x4 __attribute__((ext_vector_type(4)));
typedef short bf16x8 __attribute__((ext_vector_type(8)));   // 8 bf16 in 4 VGPRs (guide §3)
typedef unsigned short u16;

__device__ __forceinline__ u16 f2bf(float f) {
  uint32_t u = __float_as_uint(f);
  u += 0x7FFFu + ((u >> 16) & 1u);   // RNE
  return (u16)(u >> 16);
}

// ---------------- fp32 -> bf16 convert ----------------
__global__ void cvt_kernel(const float* __restrict__ src, u16* __restrict__ dst, int n4) {
  int i = blockIdx.x * blockDim.x + threadIdx.x;
  if (i >= n4) return;
  float4 v = reinterpret_cast<const float4*>(src)[i];
  ushort4 o;
  o.x = f2bf(v.x); o.y = f2bf(v.y); o.z = f2bf(v.z); o.w = f2bf(v.w);
  reinterpret_cast<ushort4*>(dst)[i] = o;
}

// ---------------- NT GEMM: C[i][j] = sum_k A[i][k] * W[j][k] ----------------
// M=8192, N=768, K=768. Tile 128x128, BK=32, 4 waves, each wave 64x64 (4x4 frags).
// MODE 0: bf16 out scattered to [B,H,S,DK].  MODE 1: fp32 out row-major [M][N].
#define BM 128
#define BN 128
#define BK 32

template<int MODE>
__launch_bounds__(256)
__global__ void gemm_nt(const u16* __restrict__ A, const u16* __restrict__ W,
                        void* __restrict__ Cout) {
  __shared__ __align__(16) u16 As[BM*BK];
  __shared__ __align__(16) u16 Ws[BN*BK];
  const int t    = threadIdx.x;
  const int lane = t & 63;
  const int wave = t >> 6;
  const int bm = blockIdx.x * BM;
  const int bn = blockIdx.y * BN;
  const int wr = (wave >> 1) * 64;
  const int wc = (wave & 1) * 64;
  const int r16 = lane & 15;
  const int g   = lane >> 4;

  f32x4 acc[4][4] = {};

  // staging: 512 chunks of 16B per matrix; chunk c -> row c>>2, col (c&3)*8
  const int c0row = t >> 2,          c0col = (t & 3) * 8;
  const int c1row = (t + 256) >> 2,  c1col = (t & 3) * 8;

  for (int kt = 0; kt < DMODEL; kt += BK) {
    uint4 a0 = *reinterpret_cast<const uint4*>(A + (size_t)(bm + c0row)*DMODEL + kt + c0col);
    uint4 a1 = *reinterpret_cast<const uint4*>(A + (size_t)(bm + c1row)*DMODEL + kt + c1col);
    uint4 w0 = *reinterpret_cast<const uint4*>(W + (size_t)(bn + c0row)*DMODEL + kt + c0col);
    uint4 w1 = *reinterpret_cast<const uint4*>(W + (size_t)(bn + c1row)*DMODEL + kt + c1col);
    *reinterpret_cast<uint4*>(&As[c0row*BK + c0col]) = a0;
    *reinterpret_cast<uint4*>(&As[c1row*BK + c1col]) = a1;
    *reinterpret_cast<uint4*>(&Ws[c0row*BK + c0col]) = w0;
    *reinterpret_cast<uint4*>(&Ws[c1row*BK + c1col]) = w1;
    __syncthreads();

    bf16x8 af[4], bfr[4];
#pragma unroll
    for (int m = 0; m < 4; ++m)
      af[m] = *reinterpret_cast<const bf16x8*>(&As[(wr + m*16 + r16)*BK + g*8]);
#pragma unroll
    for (int n = 0; n < 4; ++n)
      bfr[n] = *reinterpret_cast<const bf16x8*>(&Ws[(wc + n*16 + r16)*BK + g*8]);
#pragma unroll
    for (int m = 0; m < 4; ++m)
#pragma unroll
      for (int n = 0; n < 4; ++n)
        acc[m][n] = __builtin_amdgcn_mfma_f32_16x16x32_bf16(af[m], bfr[n], acc[m][n], 0, 0, 0);
    __syncthreads();
  }

  // epilogue: C/D layout col = lane&15, row = (lane>>4)*4 + r  (guide §3, m89/m91)
  if (MODE == 0) {
    u16* Qo = (u16*)Cout;
#pragma unroll
    for (int m = 0; m < 4; ++m) {
      const int gi0 = bm + wr + m*16 + g*4;
#pragma unroll
      for (int n = 0; n < 4; ++n) {
        const int gj = bn + wc + n*16 + r16;
        const int h = gj >> 6, dc = gj & 63;
#pragma unroll
        for (int r = 0; r < 4; ++r) {
          const int gi = gi0 + r;
          const int b_ = gi >> 11, s = gi & 2047;
          Qo[((size_t)((b_*NHEADS + h)*SEQ + s) << 6) + dc] = f2bf(acc[m][n][r]);
        }
      }
    }
  } else {
    float* C = (float*)Cout;
#pragma unroll
    for (int m = 0; m < 4; ++m) {
      const int gi0 = bm + wr + m*16 + g*4;
#pragma unroll
      for (int n = 0; n < 4; ++n) {
        const int gj = bn + wc + n*16 + r16;
#pragma unroll
        for (int r = 0; r < 4; ++r)
          C[(size_t)(gi0 + r)*DMODEL + gj] = acc[m][n][r];
      }
    }
  }
}

// ---------------- causal flash attention ----------------
// block = (qt, h, b); 256 threads = 4 waves x 16 q-rows; KV tiles of 64.
// K_lds swizzled [64][64]; Vt_lds = V^T swizzled [64 d][64 kv]; P via wave-private LDS.
__launch_bounds__(256)
__global__ void attn_kernel(const u16* __restrict__ Qg, const u16* __restrict__ Kg,
                            const u16* __restrict__ Vg, u16* __restrict__ Og) {
  __shared__ __align__(16) u16 Ks[64*64];
  __shared__ __align__(16) u16 Vt[64*64];
  __shared__ __align__(16) u16 Ps[4*16*64];
  const int t    = threadIdx.x;
  const int lane = t & 63;
  const int wave = t >> 6;
  const int qt = blockIdx.x;
  const int h  = blockIdx.y;
  const int b  = blockIdx.z;
  const int q0 = qt * 64;
  const int r16 = lane & 15;
  const int g   = lane >> 4;
  const size_t bh = (size_t)(b*NHEADS + h) * SEQ * DK;
  const u16* Qb = Qg + bh;
  const u16* Kb = Kg + bh;
  const u16* Vb = Vg + bh;

  // Q fragments in registers: A-layout row = lane&15, k = 8*(lane>>4)+e (+32*kc)
  bf16x8 aq[2];
  const int qrow = q0 + wave*16 + r16;
#pragma unroll
  for (int kc = 0; kc < 2; ++kc)
    aq[kc] = *reinterpret_cast<const bf16x8*>(Qb + (size_t)qrow*DK + kc*32 + g*8);

  f32x4 o[4] = {};
  float mrun[4], lrun[4];
#pragma unroll
  for (int r = 0; r < 4; ++r) { mrun[r] = -__builtin_inff(); lrun[r] = 0.f; }

  const int s0row = t >> 3, scol = (t & 7) * 8;
  const int s1row = (t + 256) >> 3;

  for (int kt = 0; kt <= qt; ++kt) {
    const int kv0 = kt * 64;
    // ---- stage K (b128, swizzled) and V^T (scalar scatter, swizzled) ----
#pragma unroll
    for (int j = 0; j < 2; ++j) {
      const int row = (j == 0) ? s0row : s1row;
      uint4 kvec = *reinterpret_cast<const uint4*>(Kb + (size_t)(kv0 + row)*DK + scol);
      *reinterpret_cast<uint4*>((char*)Ks + ((row*128 + scol*2) ^ ((row & 7) << 4))) = kvec;
      uint4 vvec = *reinterpret_cast<const uint4*>(Vb + (size_t)(kv0 + row)*DK + scol);
      const u16* pv = reinterpret_cast<const u16*>(&vvec);
#pragma unroll
      for (int jj = 0; jj < 8; ++jj) {
        const int d = scol + jj;
        *reinterpret_cast<u16*>((char*)Vt + ((d*128 + row*2) ^ ((d & 7) << 4))) = pv[jj];
      }
    }
    __syncthreads();

    // ---- S = Q K^T (4 col-blocks of 16 kv) ----
    f32x4 sfr[4];
#pragma unroll
    for (int nb = 0; nb < 4; ++nb) {
      f32x4 a = {};
#pragma unroll
      for (int kc = 0; kc < 2; ++kc) {
        const int row = nb*16 + r16;
        bf16x8 bk = *reinterpret_cast<const bf16x8*>(
            (char*)Ks + ((row*128 + kc*64 + g*16) ^ ((row & 7) << 4)));
        a = __builtin_amdgcn_mfma_f32_16x16x32_bf16(aq[kc], bk, a, 0, 0, 0);
      }
      sfr[nb] = a;
    }

    // ---- scale, causal mask, online softmax (rows spread over 16-lane groups) ----
    const bool diag = (kt == qt);
#pragma unroll
    for (int r = 0; r < 4; ++r) {
      const int qr = q0 + wave*16 + g*4 + r;
      float sv[4];
      float mt = -__builtin_inff();
#pragma unroll
      for (int nb = 0; nb < 4; ++nb) {
        float xs = sfr[nb][r] * 0.125f;
        if (diag && (kv0 + nb*16 + r16 > qr)) xs = -__builtin_inff();
        sv[nb] = xs;
        mt = fmaxf(mt, xs);
      }
#pragma unroll
      for (int mm = 1; mm < 16; mm <<= 1) mt = fmaxf(mt, __shfl_xor(mt, mm));
      const float mnew = fmaxf(mrun[r], mt);
      const float corr = __expf(mrun[r] - mnew);   // exp(-inf)=0 on first tile
      float psum = 0.f;
#pragma unroll
      for (int nb = 0; nb < 4; ++nb) {
        const float p = __expf(sv[nb] - mnew);
        sv[nb] = p;
        psum += p;
      }
#pragma unroll
      for (int mm = 1; mm < 16; mm <<= 1) psum += __shfl_xor(psum, mm);
      lrun[r] = lrun[r]*corr + psum;
      mrun[r] = mnew;
#pragma unroll
      for (int ob = 0; ob < 4; ++ob) o[ob][r] *= corr;
      // P (C-layout) -> wave-private LDS, bf16, swizzled
      const int prow = g*4 + r;
#pragma unroll
      for (int nb = 0; nb < 4; ++nb)
        *reinterpret_cast<u16*>((char*)Ps + wave*2048 +
            ((prow*128 + (nb*16 + r16)*2) ^ ((prow & 7) << 4))) = f2bf(sv[nb]);
    }

    // ---- O += P V ----
#pragma unroll
    for (int kc = 0; kc < 2; ++kc) {
      bf16x8 pa = *reinterpret_cast<const bf16x8*>((char*)Ps + wave*2048 +
          ((r16*128 + kc*64 + g*16) ^ ((r16 & 7) << 4)));
#pragma unroll
      for (int ob = 0; ob < 4; ++ob) {
        const int vrow = ob*16 + r16;
        bf16x8 bv = *reinterpret_cast<const bf16x8*>(
            (char*)Vt + ((vrow*128 + kc*64 + g*16) ^ ((vrow & 7) << 4)));
        o[ob] = __builtin_amdgcn_mfma_f32_16x16x32_bf16(pa, bv, o[ob], 0, 0, 0);
      }
    }
    __syncthreads();
  }

  // ---- epilogue: O/l -> [tok][DMODEL] bf16 (heads concatenated) ----
  const int tok0 = b*SEQ + q0 + wave*16 + g*4;
#pragma unroll
  for (int ob = 0; ob < 4; ++ob) {
    const int col = h*64 + ob*16 + r16;
#pragma unroll
    for (int r = 0; r < 4; ++r)
      Og[(size_t)(tok0 + r)*DMODEL + col] = f2bf(o[ob][r] / lrun[r]);
  }
}

// ---------------- launch ----------------
extern "C" void kernel_launch(void* const* d_in, const int* in_sizes, int n_in,
                              void* d_out, int out_size, void* d_ws, size_t ws_size,
                              hipStream_t stream) {
  const float* x  = (const float*)d_in[0];
  const float* wq = (const float*)d_in[1];
  const float* wk = (const float*)d_in[2];
  const float* wv = (const float*)d_in[3];
  const float* wo = (const float*)d_in[4];

  const size_t SZ_TOK = (size_t)MTOK * DMODEL * 2;   // 12.58 MB
  const size_t SZ_W   = (size_t)DMODEL * DMODEL * 2; // 1.18 MB
  char* ws = (char*)d_ws;
  size_t off = 0;
  u16* xb  = (u16*)(ws + off); off += SZ_TOK;
  u16* wqb = (u16*)(ws + off); off += SZ_W;
  u16* wkb = (u16*)(ws + off); off += SZ_W;
  u16* wvb = (u16*)(ws + off); off += SZ_W;
  u16* wob = (u16*)(ws + off); off += SZ_W;
  u16* Qw  = (u16*)(ws + off); off += SZ_TOK;
  u16* Kw  = (u16*)(ws + off); off += SZ_TOK;
  u16* Vw  = (u16*)(ws + off); off += SZ_TOK;
  u16* Ow  = (u16*)(ws + off); off += SZ_TOK;
  if (ws_size < off) return;   // fail loudly (wrong output) rather than corrupt

  const int nx4 = MTOK * DMODEL / 4;     // 1,572,864
  const int nw4 = DMODEL * DMODEL / 4;   // 147,456
  cvt_kernel<<<nx4/256, 256, 0, stream>>>(x,  xb,  nx4);
  cvt_kernel<<<nw4/256, 256, 0, stream>>>(wq, wqb, nw4);
  cvt_kernel<<<nw4/256, 256, 0, stream>>>(wk, wkb, nw4);
  cvt_kernel<<<nw4/256, 256, 0, stream>>>(wv, wvb, nw4);
  cvt_kernel<<<nw4/256, 256, 0, stream>>>(wo, wob, nw4);

  dim3 gg(MTOK/BM, DMODEL/BN);  // 64 x 6
  gemm_nt<0><<<gg, 256, 0, stream>>>(xb, wqb, (void*)Qw);
  gemm_nt<0><<<gg, 256, 0, stream>>>(xb, wkb, (void*)Kw);
  gemm_nt<0><<<gg, 256, 0, stream>>>(xb, wvb, (void*)Vw);

  attn_kernel<<<dim3(SEQ/64, NHEADS, BATCH), 256, 0, stream>>>(Qw, Kw, Vw, Ow);

  gemm_nt<1><<<gg, 256, 0, stream>>>(Ow, wob, d_out);
}

// Round 2
// 274.567 us; speedup vs baseline: 1.5012x; 1.5012x over previous
//
#include <hip/hip_runtime.h>
#include <stdint.h>

#define DMODEL 768
#define NHEADS 12
#define DK 64
#define BATCH 4
#define SEQ 2048
#define MTOK (BATCH*SEQ)   // 8192 tokens

typedef float f32x4 __attribute__((ext_vector_type(4)));
typedef short bf16x8 __attribute__((ext_vector_type(8)));
typedef unsigned short u16;

__device__ __forceinline__ u16 f2bf(float f) {
  uint32_t u = __float_as_uint(f);
  u += 0x7FFFu + ((u >> 16) & 1u);   // RNE
  return (u16)(u >> 16);
}

// ---------------- fp32 -> bf16 convert ----------------
__global__ void cvt_kernel(const float* __restrict__ src, u16* __restrict__ dst, int n4) {
  int i = blockIdx.x * blockDim.x + threadIdx.x;
  if (i >= n4) return;
  float4 v = reinterpret_cast<const float4*>(src)[i];
  ushort4 o;
  o.x = f2bf(v.x); o.y = f2bf(v.y); o.z = f2bf(v.z); o.w = f2bf(v.w);
  reinterpret_cast<ushort4*>(dst)[i] = o;
}

// ---------------- NT GEMM: C[i][j] = sum_k A[i][k] * W[j][k] ----------------
// M=8192, N=768, K=768. Tile 128x128, BK=32, 8 waves (wave = 32x64 = 2x4 frags),
// reg-prefetch double-buffered LDS, one barrier per K-step.
// MODE 0: bf16 out scattered to [B,H,S,DK].
// MODE 1: fp32 out row-major [M][N].
// MODE 2: bf16 out transposed to [B,H,DK,S]  (for V^T).
#define BM 128
#define BN 128
#define BK 32

template<int MODE>
__launch_bounds__(512)
__global__ void gemm_nt(const u16* __restrict__ A, const u16* __restrict__ W,
                        void* __restrict__ Cout) {
  __shared__ __align__(16) u16 As[2][BM*BK];
  __shared__ __align__(16) u16 Ws[2][BN*BK];
  const int t    = threadIdx.x;
  const int lane = t & 63;
  const int wave = t >> 6;              // 0..7
  const int bm = blockIdx.x * BM;
  const int bn = blockIdx.y * BN;
  const int wr = (wave >> 1) * 32;      // 4 row-groups of 32
  const int wc = (wave & 1) * 64;       // 2 col-groups of 64
  const int r16 = lane & 15;
  const int g   = lane >> 4;

  f32x4 acc[2][4] = {};

  // staging: 512 chunks of 16B per matrix; thread t -> row t>>2, col (t&3)*8
  const int crow = t >> 2, ccol = (t & 3) * 8;
  const size_t aoff = (size_t)(bm + crow) * DMODEL + ccol;
  const size_t woff = (size_t)(bn + crow) * DMODEL + ccol;

  // prologue: stage K-step 0 into buffer 0
  {
    uint4 a0 = *reinterpret_cast<const uint4*>(A + aoff);
    uint4 w0 = *reinterpret_cast<const uint4*>(W + woff);
    *reinterpret_cast<uint4*>(&As[0][crow*BK + ccol]) = a0;
    *reinterpret_cast<uint4*>(&Ws[0][crow*BK + ccol]) = w0;
  }
  __syncthreads();

  const int NK = DMODEL / BK;           // 24
  for (int kt = 0; kt < NK; ++kt) {
    const int cur = kt & 1;
    const bool nx = (kt + 1 < NK);
    uint4 a1, w1;
    if (nx) {
      a1 = *reinterpret_cast<const uint4*>(A + aoff + (size_t)(kt+1)*BK);
      w1 = *reinterpret_cast<const uint4*>(W + woff + (size_t)(kt+1)*BK);
    }
    bf16x8 af[2], bfr[4];
#pragma unroll
    for (int m = 0; m < 2; ++m)
      af[m] = *reinterpret_cast<const bf16x8*>(&As[cur][(wr + m*16 + r16)*BK + g*8]);
#pragma unroll
    for (int n = 0; n < 4; ++n)
      bfr[n] = *reinterpret_cast<const bf16x8*>(&Ws[cur][(wc + n*16 + r16)*BK + g*8]);
#pragma unroll
    for (int m = 0; m < 2; ++m)
#pragma unroll
      for (int n = 0; n < 4; ++n)
        acc[m][n] = __builtin_amdgcn_mfma_f32_16x16x32_bf16(af[m], bfr[n], acc[m][n], 0, 0, 0);
    if (nx) {
      *reinterpret_cast<uint4*>(&As[cur^1][crow*BK + ccol]) = a1;
      *reinterpret_cast<uint4*>(&Ws[cur^1][crow*BK + ccol]) = w1;
    }
    __syncthreads();
  }

  // epilogue: C/D layout col = lane&15, row = (lane>>4)*4 + r
  if (MODE == 0) {
    u16* Qo = (u16*)Cout;
#pragma unroll
    for (int m = 0; m < 2; ++m) {
      const int gi0 = bm + wr + m*16 + g*4;
#pragma unroll
      for (int n = 0; n < 4; ++n) {
        const int gj = bn + wc + n*16 + r16;
        const int h = gj >> 6, dc = gj & 63;
#pragma unroll
        for (int r = 0; r < 4; ++r) {
          const int gi = gi0 + r;
          const int b_ = gi >> 11, s = gi & 2047;
          Qo[((size_t)((b_*NHEADS + h)*SEQ + s) << 6) + dc] = f2bf(acc[m][n][r]);
        }
      }
    }
  } else if (MODE == 1) {
    float* C = (float*)Cout;
#pragma unroll
    for (int m = 0; m < 2; ++m) {
      const int gi0 = bm + wr + m*16 + g*4;
#pragma unroll
      for (int n = 0; n < 4; ++n) {
        const int gj = bn + wc + n*16 + r16;
#pragma unroll
        for (int r = 0; r < 4; ++r)
          C[(size_t)(gi0 + r)*DMODEL + gj] = acc[m][n][r];
      }
    }
  } else {
    // V^T: Vo[b][h][dc][s], 4 consecutive s per lane -> packed ushort4 (8B) store
    u16* Vo = (u16*)Cout;
#pragma unroll
    for (int m = 0; m < 2; ++m) {
      const int gi0 = bm + wr + m*16 + g*4;
      const int b_ = gi0 >> 11, s0 = gi0 & 2047;   // 4-run never crosses batch bound
#pragma unroll
      for (int n = 0; n < 4; ++n) {
        const int gj = bn + wc + n*16 + r16;
        const int h = gj >> 6, dc = gj & 63;
        ushort4 pk;
        pk.x = f2bf(acc[m][n][0]); pk.y = f2bf(acc[m][n][1]);
        pk.z = f2bf(acc[m][n][2]); pk.w = f2bf(acc[m][n][3]);
        *reinterpret_cast<ushort4*>(Vo + ((size_t)((b_*NHEADS + h)*DK + dc) * SEQ + s0)) = pk;
      }
    }
  }
}

// ---------------- causal flash attention ----------------
// block = (pair, h, b); pair handles q-tiles {pair, 31-pair} sequentially
// -> constant 33 kv-tiles per block (perfect causal balance).
// 256 threads = 4 waves x 16 q-rows. K and V^T double-buffered in LDS
// (swizzled b128 stage), V^T comes pre-transposed from the V GEMM.
__launch_bounds__(256)
__global__ void attn_kernel(const u16* __restrict__ Qg, const u16* __restrict__ Kg,
                            const u16* __restrict__ Vtg, u16* __restrict__ Og) {
  __shared__ __align__(16) u16 Ks[2][64*64];
  __shared__ __align__(16) u16 Vt[2][64*64];
  __shared__ __align__(16) u16 Ps[4*16*64];
  const int t    = threadIdx.x;
  const int lane = t & 63;
  const int wave = t >> 6;
  const int r16 = lane & 15;
  const int g   = lane >> 4;
  const int pair = blockIdx.x;          // 0..15
  const int h  = blockIdx.y;
  const int b  = blockIdx.z;
  const int qt_lo = pair, qt_hi = 31 - pair;
  const int nlo = qt_lo + 1;
  const int ntot = 33;                  // nlo + (qt_hi+1)
  const size_t bh = (size_t)(b*NHEADS + h);
  const u16* Qb  = Qg  + bh * SEQ * DK;
  const u16* Kb  = Kg  + bh * SEQ * DK;
  const u16* Vb  = Vtg + bh * DK * SEQ;   // [d][s]

  // staging: 256 threads x 2 chunks of 16B cover a 64x64 u16 tile
  const int sr0 = t >> 3, sc = (t & 7) * 8, sr1 = sr0 + 32;

  int q0 = qt_lo * 64;
  bf16x8 aq[2];
#pragma unroll
  for (int kc = 0; kc < 2; ++kc)
    aq[kc] = *reinterpret_cast<const bf16x8*>(Qb + (size_t)(q0 + wave*16 + r16)*DK + kc*32 + g*8);

  f32x4 o[4] = {};
  float mrun[4], lrun[4];
#pragma unroll
  for (int r = 0; r < 4; ++r) { mrun[r] = -__builtin_inff(); lrun[r] = 0.f; }

  // prologue: stage kv-tile 0 into buffer 0
  {
    uint4 k0 = *reinterpret_cast<const uint4*>(Kb + (size_t)sr0*DK + sc);
    uint4 k1 = *reinterpret_cast<const uint4*>(Kb + (size_t)sr1*DK + sc);
    uint4 v0 = *reinterpret_cast<const uint4*>(Vb + (size_t)sr0*SEQ + sc);
    uint4 v1 = *reinterpret_cast<const uint4*>(Vb + (size_t)sr1*SEQ + sc);
    *reinterpret_cast<uint4*>((char*)Ks[0] + ((sr0*128 + sc*2) ^ ((sr0 & 7) << 4))) = k0;
    *reinterpret_cast<uint4*>((char*)Ks[0] + ((sr1*128 + sc*2) ^ ((sr1 & 7) << 4))) = k1;
    *reinterpret_cast<uint4*>((char*)Vt[0] + ((sr0*128 + sc*2) ^ ((sr0 & 7) << 4))) = v0;
    *reinterpret_cast<uint4*>((char*)Vt[0] + ((sr1*128 + sc*2) ^ ((sr1 & 7) << 4))) = v1;
  }
  __syncthreads();

  for (int i = 0; i < ntot; ++i) {
    const int cur = i & 1;
    const int kvt = (i < nlo) ? i : (i - nlo);
    const int kv0 = kvt * 64;
    const bool nx = (i + 1 < ntot);
    uint4 kn0, kn1, vn0, vn1;
    if (nx) {   // issue next tile's loads early (hide HBM/L2 latency under compute)
      const int nkvt = ((i+1) < nlo) ? (i+1) : (i+1 - nlo);
      const int nkv0 = nkvt * 64;
      kn0 = *reinterpret_cast<const uint4*>(Kb + (size_t)(nkv0 + sr0)*DK + sc);
      kn1 = *reinterpret_cast<const uint4*>(Kb + (size_t)(nkv0 + sr1)*DK + sc);
      vn0 = *reinterpret_cast<const uint4*>(Vb + (size_t)sr0*SEQ + nkv0 + sc);
      vn1 = *reinterpret_cast<const uint4*>(Vb + (size_t)sr1*SEQ + nkv0 + sc);
    }

    // ---- S = Q K^T ----
    f32x4 sfr[4];
#pragma unroll
    for (int nb = 0; nb < 4; ++nb) {
      f32x4 a = {};
#pragma unroll
      for (int kc = 0; kc < 2; ++kc) {
        const int row = nb*16 + r16;
        bf16x8 bk = *reinterpret_cast<const bf16x8*>(
            (char*)Ks[cur] + ((row*128 + kc*64 + g*16) ^ ((row & 7) << 4)));
        a = __builtin_amdgcn_mfma_f32_16x16x32_bf16(aq[kc], bk, a, 0, 0, 0);
      }
      sfr[nb] = a;
    }

    // ---- scale, causal mask, online softmax ----
    const bool diag = (i == nlo-1) || (i == ntot-1);
#pragma unroll
    for (int r = 0; r < 4; ++r) {
      const int qr = q0 + wave*16 + g*4 + r;
      float sv[4];
      float mt = -__builtin_inff();
#pragma unroll
      for (int nb = 0; nb < 4; ++nb) {
        float xs = sfr[nb][r] * 0.125f;
        if (diag && (kv0 + nb*16 + r16 > qr)) xs = -__builtin_inff();
        sv[nb] = xs;
        mt = fmaxf(mt, xs);
      }
#pragma unroll
      for (int mm = 1; mm < 16; mm <<= 1) mt = fmaxf(mt, __shfl_xor(mt, mm));
      const float mnew = fmaxf(mrun[r], mt);
      const float corr = __expf(mrun[r] - mnew);
      float psum = 0.f;
#pragma unroll
      for (int nb = 0; nb < 4; ++nb) {
        const float p = __expf(sv[nb] - mnew);
        sv[nb] = p;
        psum += p;
      }
#pragma unroll
      for (int mm = 1; mm < 16; mm <<= 1) psum += __shfl_xor(psum, mm);
      lrun[r] = lrun[r]*corr + psum;
      mrun[r] = mnew;
#pragma unroll
      for (int ob = 0; ob < 4; ++ob) o[ob][r] *= corr;
      const int prow = g*4 + r;
#pragma unroll
      for (int nb = 0; nb < 4; ++nb)
        *reinterpret_cast<u16*>((char*)Ps + wave*2048 +
            ((prow*128 + (nb*16 + r16)*2) ^ ((prow & 7) << 4))) = f2bf(sv[nb]);
    }

    // ---- O += P V ----
#pragma unroll
    for (int kc = 0; kc < 2; ++kc) {
      bf16x8 pa = *reinterpret_cast<const bf16x8*>((char*)Ps + wave*2048 +
          ((r16*128 + kc*64 + g*16) ^ ((r16 & 7) << 4)));
#pragma unroll
      for (int ob = 0; ob < 4; ++ob) {
        const int vrow = ob*16 + r16;
        bf16x8 bv = *reinterpret_cast<const bf16x8*>(
            (char*)Vt[cur] + ((vrow*128 + kc*64 + g*16) ^ ((vrow & 7) << 4)));
        o[ob] = __builtin_amdgcn_mfma_f32_16x16x32_bf16(pa, bv, o[ob], 0, 0, 0);
      }
    }

    if (nx) {   // write-late into the other buffer (read last iter, safe now)
      const int nb_ = cur ^ 1;
      *reinterpret_cast<uint4*>((char*)Ks[nb_] + ((sr0*128 + sc*2) ^ ((sr0 & 7) << 4))) = kn0;
      *reinterpret_cast<uint4*>((char*)Ks[nb_] + ((sr1*128 + sc*2) ^ ((sr1 & 7) << 4))) = kn1;
      *reinterpret_cast<uint4*>((char*)Vt[nb_] + ((sr0*128 + sc*2) ^ ((sr0 & 7) << 4))) = vn0;
      *reinterpret_cast<uint4*>((char*)Vt[nb_] + ((sr1*128 + sc*2) ^ ((sr1 & 7) << 4))) = vn1;
    }
    __syncthreads();

    if (i == nlo - 1) {
      // ---- epilogue for the low q-tile, then switch to the high q-tile ----
      const int tok0 = b*SEQ + q0 + wave*16 + g*4;
#pragma unroll
      for (int ob = 0; ob < 4; ++ob) {
        const int col = h*64 + ob*16 + r16;
#pragma unroll
        for (int r = 0; r < 4; ++r)
          Og[(size_t)(tok0 + r)*DMODEL + col] = f2bf(o[ob][r] / lrun[r]);
      }
      q0 = qt_hi * 64;
#pragma unroll
      for (int kc = 0; kc < 2; ++kc)
        aq[kc] = *reinterpret_cast<const bf16x8*>(Qb + (size_t)(q0 + wave*16 + r16)*DK + kc*32 + g*8);
#pragma unroll
      for (int r = 0; r < 4; ++r) { mrun[r] = -__builtin_inff(); lrun[r] = 0.f; }
#pragma unroll
      for (int ob = 0; ob < 4; ++ob) o[ob] = (f32x4){0.f,0.f,0.f,0.f};
    }
  }

  // ---- epilogue for the high q-tile ----
  const int tok0 = b*SEQ + q0 + wave*16 + g*4;
#pragma unroll
  for (int ob = 0; ob < 4; ++ob) {
    const int col = h*64 + ob*16 + r16;
#pragma unroll
    for (int r = 0; r < 4; ++r)
      Og[(size_t)(tok0 + r)*DMODEL + col] = f2bf(o[ob][r] / lrun[r]);
  }
}

// ---------------- launch ----------------
extern "C" void kernel_launch(void* const* d_in, const int* in_sizes, int n_in,
                              void* d_out, int out_size, void* d_ws, size_t ws_size,
                              hipStream_t stream) {
  const float* x  = (const float*)d_in[0];
  const float* wq = (const float*)d_in[1];
  const float* wk = (const float*)d_in[2];
  const float* wv = (const float*)d_in[3];
  const float* wo = (const float*)d_in[4];

  const size_t SZ_TOK = (size_t)MTOK * DMODEL * 2;
  const size_t SZ_W   = (size_t)DMODEL * DMODEL * 2;
  char* ws = (char*)d_ws;
  size_t off = 0;
  u16* xb  = (u16*)(ws + off); off += SZ_TOK;
  u16* wqb = (u16*)(ws + off); off += SZ_W;
  u16* wkb = (u16*)(ws + off); off += SZ_W;
  u16* wvb = (u16*)(ws + off); off += SZ_W;
  u16* wob = (u16*)(ws + off); off += SZ_W;
  u16* Qw  = (u16*)(ws + off); off += SZ_TOK;
  u16* Kw  = (u16*)(ws + off); off += SZ_TOK;
  u16* Vtw = (u16*)(ws + off); off += SZ_TOK;   // [B,H,DK,S]
  u16* Ow  = (u16*)(ws + off); off += SZ_TOK;
  if (ws_size < off) return;

  const int nx4 = MTOK * DMODEL / 4;
  const int nw4 = DMODEL * DMODEL / 4;
  cvt_kernel<<<nx4/256, 256, 0, stream>>>(x,  xb,  nx4);
  cvt_kernel<<<nw4/256, 256, 0, stream>>>(wq, wqb, nw4);
  cvt_kernel<<<nw4/256, 256, 0, stream>>>(wk, wkb, nw4);
  cvt_kernel<<<nw4/256, 256, 0, stream>>>(wv, wvb, nw4);
  cvt_kernel<<<nw4/256, 256, 0, stream>>>(wo, wob, nw4);

  dim3 gg(MTOK/BM, DMODEL/BN);  // 64 x 6
  gemm_nt<0><<<gg, 512, 0, stream>>>(xb, wqb, (void*)Qw);
  gemm_nt<0><<<gg, 512, 0, stream>>>(xb, wkb, (void*)Kw);
  gemm_nt<2><<<gg, 512, 0, stream>>>(xb, wvb, (void*)Vtw);

  attn_kernel<<<dim3(16, NHEADS, BATCH), 256, 0, stream>>>(Qw, Kw, Vtw, Ow);

  gemm_nt<1><<<gg, 512, 0, stream>>>(Ow, wob, d_out);
}

// Round 3
// 243.033 us; speedup vs baseline: 1.6960x; 1.1298x over previous
//
#include <hip/hip_runtime.h>
#include <stdint.h>

#define DMODEL 768
#define NHEADS 12
#define DK 64
#define BATCH 4
#define SEQ 2048
#define MTOK (BATCH*SEQ)   // 8192 tokens

typedef float f32x4 __attribute__((ext_vector_type(4)));
typedef short bf16x8 __attribute__((ext_vector_type(8)));
typedef unsigned short u16;

__device__ __forceinline__ u16 f2bf(float f) {
  uint32_t u = __float_as_uint(f);
  u += 0x7FFFu + ((u >> 16) & 1u);   // RNE
  return (u16)(u >> 16);
}

// async global->LDS, 16B per lane; LDS dest is wave-uniform base + lane*16
#define GLDS16(g, l) __builtin_amdgcn_global_load_lds( \
    (const __attribute__((address_space(1))) unsigned int*)(g), \
    (__attribute__((address_space(3))) unsigned int*)(l), 16, 0, 0)

// ---------------- fp32 -> bf16 convert ----------------
__global__ void cvt_kernel(const float* __restrict__ src, u16* __restrict__ dst, int n4) {
  int i = blockIdx.x * blockDim.x + threadIdx.x;
  if (i >= n4) return;
  float4 v = reinterpret_cast<const float4*>(src)[i];
  ushort4 o;
  o.x = f2bf(v.x); o.y = f2bf(v.y); o.z = f2bf(v.z); o.w = f2bf(v.w);
  reinterpret_cast<ushort4*>(dst)[i] = o;
}

__global__ void cvt_w4(const float* __restrict__ w0, const float* __restrict__ w1,
                       const float* __restrict__ w2, const float* __restrict__ w3,
                       u16* __restrict__ dst, int n4) {
  int i = blockIdx.x * blockDim.x + threadIdx.x;
  if (i >= n4) return;
  const float* src = (blockIdx.y == 0) ? w0 : (blockIdx.y == 1) ? w1 : (blockIdx.y == 2) ? w2 : w3;
  float4 v = reinterpret_cast<const float4*>(src)[i];
  ushort4 o;
  o.x = f2bf(v.x); o.y = f2bf(v.y); o.z = f2bf(v.z); o.w = f2bf(v.w);
  reinterpret_cast<ushort4*>(dst + (size_t)blockIdx.y * DMODEL * DMODEL)[i] = o;
}

// ---------------- shared GEMM main loop ----------------
// Tile 128x128, BK=32, 8 waves (wave = 32x64 = 2x4 frags), global_load_lds
// double-buffered, chunk-XOR LDS swizzle (source-preswizzled, linear LDS dest).
#define BM 128
#define BN 128
#define BK 32

__device__ __forceinline__ void gemm_loop(const u16* __restrict__ A, const u16* __restrict__ W,
                                          int bm, int bn, int t, u16* As, u16* Ws,
                                          f32x4 (&acc)[2][4]) {
  const int lane = t & 63;
  const int wave = t >> 6;
  const int r16 = lane & 15, g = lane >> 4;
  const int wr = (wave >> 1) * 32;
  const int wc = (wave & 1) * 64;
  // staging: thread t -> LDS slot t*16B = (row t>>2, chunk t&3); holds global
  // chunk (t&3)^((t>>3)&3) of row t>>2  (chunk-XOR swizzle via source address)
  const int crow = t >> 2;
  const int cchunk = (t & 3) ^ ((t >> 3) & 3);
  const size_t aoff = (size_t)(bm + crow) * DMODEL + cchunk * 8;
  const size_t woff = (size_t)(bn + crow) * DMODEL + cchunk * 8;

  GLDS16(A + aoff, As + t * 8);
  GLDS16(W + woff, Ws + t * 8);
  __syncthreads();

  const int NK = DMODEL / BK;   // 24
  for (int kt = 0; kt < NK; ++kt) {
    const int cur = kt & 1;
    if (kt + 1 < NK) {
      GLDS16(A + aoff + (size_t)(kt + 1) * BK, As + (cur ^ 1) * 4096 + t * 8);
      GLDS16(W + woff + (size_t)(kt + 1) * BK, Ws + (cur ^ 1) * 4096 + t * 8);
    }
    bf16x8 af[2], bfr[4];
#pragma unroll
    for (int m = 0; m < 2; ++m) {
      const int row = wr + m * 16 + r16;
      af[m] = *reinterpret_cast<const bf16x8*>(&As[cur * 4096 + row * 32 + ((g ^ ((row >> 1) & 3)) * 8)]);
    }
#pragma unroll
    for (int n = 0; n < 4; ++n) {
      const int row = wc + n * 16 + r16;
      bfr[n] = *reinterpret_cast<const bf16x8*>(&Ws[cur * 4096 + row * 32 + ((g ^ ((row >> 1) & 3)) * 8)]);
    }
#pragma unroll
    for (int m = 0; m < 2; ++m)
#pragma unroll
      for (int n = 0; n < 4; ++n)
        acc[m][n] = __builtin_amdgcn_mfma_f32_16x16x32_bf16(af[m], bfr[n], acc[m][n], 0, 0, 0);
    __syncthreads();
  }
}

// Fused QKV projection: z=0 Q (pre-scaled by 0.125), z=1 K, z=2 V^T
__launch_bounds__(512)
__global__ void qkv_gemm(const u16* __restrict__ A, const u16* __restrict__ wAll,
                         u16* __restrict__ Qw, u16* __restrict__ Kw, u16* __restrict__ Vtw) {
  __shared__ __align__(16) u16 As[2 * BM * BK];
  __shared__ __align__(16) u16 Ws[2 * BN * BK];
  const int t = threadIdx.x;
  const int lane = t & 63, wave = t >> 6;
  const int r16 = lane & 15, g = lane >> 4;
  const int bm = blockIdx.x * BM, bn = blockIdx.y * BN;
  const int z = blockIdx.z;
  const u16* W = wAll + (size_t)z * DMODEL * DMODEL;
  const int wr = (wave >> 1) * 32, wc = (wave & 1) * 64;

  f32x4 acc[2][4] = {};
  gemm_loop(A, W, bm, bn, t, As, Ws, acc);

  if (z <= 1) {
    u16* Qo = (z == 0) ? Qw : Kw;
    const float scl = (z == 0) ? 0.125f : 1.0f;   // 2^-3: lossless bf16 pre-scale
#pragma unroll
    for (int m = 0; m < 2; ++m) {
      const int gi0 = bm + wr + m * 16 + g * 4;
#pragma unroll
      for (int n = 0; n < 4; ++n) {
        const int gj = bn + wc + n * 16 + r16;
        const int h = gj >> 6, dc = gj & 63;
#pragma unroll
        for (int r = 0; r < 4; ++r) {
          const int gi = gi0 + r;
          const int b_ = gi >> 11, s = gi & 2047;
          Qo[((size_t)((b_ * NHEADS + h) * SEQ + s) << 6) + dc] = f2bf(acc[m][n][r] * scl);
        }
      }
    }
  } else {
    // V^T: Vo[b][h][dc][s], 4 consecutive s per lane -> packed ushort4 store
#pragma unroll
    for (int m = 0; m < 2; ++m) {
      const int gi0 = bm + wr + m * 16 + g * 4;
      const int b_ = gi0 >> 11, s0 = gi0 & 2047;
#pragma unroll
      for (int n = 0; n < 4; ++n) {
        const int gj = bn + wc + n * 16 + r16;
        const int h = gj >> 6, dc = gj & 63;
        ushort4 pk;
        pk.x = f2bf(acc[m][n][0]); pk.y = f2bf(acc[m][n][1]);
        pk.z = f2bf(acc[m][n][2]); pk.w = f2bf(acc[m][n][3]);
        *reinterpret_cast<ushort4*>(Vtw + ((size_t)((b_ * NHEADS + h) * DK + dc) * SEQ + s0)) = pk;
      }
    }
  }
}

// Output projection: fp32 out row-major [M][N]
__launch_bounds__(512)
__global__ void out_gemm(const u16* __restrict__ A, const u16* __restrict__ W,
                         float* __restrict__ C) {
  __shared__ __align__(16) u16 As[2 * BM * BK];
  __shared__ __align__(16) u16 Ws[2 * BN * BK];
  const int t = threadIdx.x;
  const int lane = t & 63, wave = t >> 6;
  const int r16 = lane & 15, g = lane >> 4;
  const int bm = blockIdx.x * BM, bn = blockIdx.y * BN;
  const int wr = (wave >> 1) * 32, wc = (wave & 1) * 64;

  f32x4 acc[2][4] = {};
  gemm_loop(A, W, bm, bn, t, As, Ws, acc);

#pragma unroll
  for (int m = 0; m < 2; ++m) {
    const int gi0 = bm + wr + m * 16 + g * 4;
#pragma unroll
    for (int n = 0; n < 4; ++n) {
      const int gj = bn + wc + n * 16 + r16;
#pragma unroll
      for (int r = 0; r < 4; ++r)
        C[(size_t)(gi0 + r) * DMODEL + gj] = acc[m][n][r];
    }
  }
}

// ---------------- causal flash attention ----------------
// One 64-row q-tile per block, LPT (descending-work) launch order.
// 256 threads = 4 waves x 16 q-rows; KV tiles of 64, double-buffered.
// K staged with pi-permuted rows (pi(r) = (r&15)*4 + (r>>4)) so each lane's
// 4 P-values are 4 consecutive kv -> cvt_pk + single ds_write_b64.
__launch_bounds__(256)
__global__ void attn_kernel(const u16* __restrict__ Qg, const u16* __restrict__ Kg,
                            const u16* __restrict__ Vtg, u16* __restrict__ Og) {
  __shared__ __align__(16) u16 Ks[2][64 * 64];
  __shared__ __align__(16) u16 Vt[2][64 * 64];
  __shared__ __align__(16) u16 Ps[4 * 16 * 64];
  const int t = threadIdx.x;
  const int lane = t & 63, wave = t >> 6;
  const int r16 = lane & 15, g = lane >> 4;
  const int bx = blockIdx.x;            // 0..1535
  const int qt = 31 - (bx / 48);        // largest q-tiles dispatched first (LPT)
  const int hb = bx % 48;
  const int h = hb % NHEADS, b = hb / NHEADS;
  const int q0 = qt * 64;
  const int ntot = qt + 1;
  const size_t bh = (size_t)(b * NHEADS + h);
  const u16* Qb = Qg + bh * SEQ * DK;
  const u16* Kb = Kg + bh * SEQ * DK;
  const u16* Vb = Vtg + bh * DK * SEQ;  // [d][s]

  const int sr0 = t >> 3, sc = (t & 7) * 8, sr1 = sr0 + 32;
  const int kp0 = ((sr0 & 15) << 2) | (sr0 >> 4);   // pi(sr0)
  const int kp1 = ((sr1 & 15) << 2) | (sr1 >> 4);   // pi(sr1)

  // Q fragments (Q pre-scaled by 0.125 in projection GEMM)
  bf16x8 aq[2];
  const int qrow = q0 + wave * 16 + r16;
#pragma unroll
  for (int kc = 0; kc < 2; ++kc)
    aq[kc] = *reinterpret_cast<const bf16x8*>(Qb + (size_t)qrow * DK + kc * 32 + g * 8);

  f32x4 o[4] = {};
  float mrun[4], lrun[4];
#pragma unroll
  for (int r = 0; r < 4; ++r) { mrun[r] = -__builtin_inff(); lrun[r] = 0.f; }

  const int qrbase = q0 + wave * 16 + g * 4;
  const int kvb = r16 * 4;

  // prologue: stage kv-tile 0 into buffer 0
  {
    uint4 k0 = *reinterpret_cast<const uint4*>(Kb + (size_t)kp0 * DK + sc);
    uint4 k1 = *reinterpret_cast<const uint4*>(Kb + (size_t)kp1 * DK + sc);
    uint4 v0 = *reinterpret_cast<const uint4*>(Vb + (size_t)sr0 * SEQ + sc);
    uint4 v1 = *reinterpret_cast<const uint4*>(Vb + (size_t)sr1 * SEQ + sc);
    *reinterpret_cast<uint4*>((char*)Ks[0] + ((sr0 * 128 + sc * 2) ^ ((sr0 & 7) << 4))) = k0;
    *reinterpret_cast<uint4*>((char*)Ks[0] + ((sr1 * 128 + sc * 2) ^ ((sr1 & 7) << 4))) = k1;
    *reinterpret_cast<uint4*>((char*)Vt[0] + ((sr0 * 128 + sc * 2) ^ ((sr0 & 7) << 4))) = v0;
    *reinterpret_cast<uint4*>((char*)Vt[0] + ((sr1 * 128 + sc * 2) ^ ((sr1 & 7) << 4))) = v1;
  }
  __syncthreads();

  for (int i = 0; i < ntot; ++i) {
    const int cur = i & 1;
    const int kv0 = i * 64;
    const bool nx = (i + 1 < ntot);
    uint4 kn0, kn1, vn0, vn1;
    if (nx) {
      const int nkv0 = kv0 + 64;
      kn0 = *reinterpret_cast<const uint4*>(Kb + (size_t)(nkv0 + kp0) * DK + sc);
      kn1 = *reinterpret_cast<const uint4*>(Kb + (size_t)(nkv0 + kp1) * DK + sc);
      vn0 = *reinterpret_cast<const uint4*>(Vb + (size_t)sr0 * SEQ + nkv0 + sc);
      vn1 = *reinterpret_cast<const uint4*>(Vb + (size_t)sr1 * SEQ + nkv0 + sc);
    }

    // ---- S = Q K^T (K rows pi-permuted: col r16 of block nb = kv r16*4+nb) ----
    f32x4 sfr[4];
#pragma unroll
    for (int nb = 0; nb < 4; ++nb) {
      f32x4 a = {};
#pragma unroll
      for (int kc = 0; kc < 2; ++kc) {
        const int row = nb * 16 + r16;
        bf16x8 bk = *reinterpret_cast<const bf16x8*>(
            (char*)Ks[cur] + ((row * 128 + kc * 64 + g * 16) ^ ((row & 7) << 4)));
        a = __builtin_amdgcn_mfma_f32_16x16x32_bf16(aq[kc], bk, a, 0, 0, 0);
      }
      sfr[nb] = a;
    }

    // ---- causal mask + online softmax ----
    const bool diag = (i == qt);
#pragma unroll
    for (int r = 0; r < 4; ++r) {
      const int qr = qrbase + r;
      float sv[4];
#pragma unroll
      for (int nb = 0; nb < 4; ++nb) {
        float xs = sfr[nb][r];
        if (diag && (kv0 + kvb + nb > qr)) xs = -__builtin_inff();
        sv[nb] = xs;
      }
      float mt = fmaxf(fmaxf(sv[0], sv[1]), fmaxf(sv[2], sv[3]));
#pragma unroll
      for (int mm = 1; mm < 16; mm <<= 1) mt = fmaxf(mt, __shfl_xor(mt, mm));
      if (!__all(mt <= mrun[r])) {      // exact skip (THR=0)
        const float mnew = fmaxf(mrun[r], mt);
        const float corr = __expf(mrun[r] - mnew);
        lrun[r] *= corr;
#pragma unroll
        for (int ob = 0; ob < 4; ++ob) o[ob][r] *= corr;
        mrun[r] = mnew;
      }
      const float m_ = mrun[r];
      const float p0 = __expf(sv[0] - m_), p1 = __expf(sv[1] - m_);
      const float p2 = __expf(sv[2] - m_), p3 = __expf(sv[3] - m_);
      float psum = (p0 + p1) + (p2 + p3);
#pragma unroll
      for (int mm = 1; mm < 16; mm <<= 1) psum += __shfl_xor(psum, mm);
      lrun[r] += psum;
      uint32_t lo, hi;
      asm("v_cvt_pk_bf16_f32 %0, %1, %2" : "=v"(lo) : "v"(p0), "v"(p1));
      asm("v_cvt_pk_bf16_f32 %0, %1, %2" : "=v"(hi) : "v"(p2), "v"(p3));
      const int prow = g * 4 + r;
      *reinterpret_cast<uint2*>((char*)Ps + wave * 2048 +
          ((prow * 128 + r16 * 8) ^ ((prow & 7) << 4))) = uint2{lo, hi};
    }

    // ---- O += P V (P in natural kv order; V natural) ----
#pragma unroll
    for (int kc = 0; kc < 2; ++kc) {
      bf16x8 pa = *reinterpret_cast<const bf16x8*>((char*)Ps + wave * 2048 +
          ((r16 * 128 + kc * 64 + g * 16) ^ ((r16 & 7) << 4)));
#pragma unroll
      for (int ob = 0; ob < 4; ++ob) {
        const int vrow = ob * 16 + r16;
        bf16x8 bv = *reinterpret_cast<const bf16x8*>(
            (char*)Vt[cur] + ((vrow * 128 + kc * 64 + g * 16) ^ ((vrow & 7) << 4)));
        o[ob] = __builtin_amdgcn_mfma_f32_16x16x32_bf16(pa, bv, o[ob], 0, 0, 0);
      }
    }

    if (nx) {   // write-late into the other buffer
      const int nb_ = cur ^ 1;
      *reinterpret_cast<uint4*>((char*)Ks[nb_] + ((sr0 * 128 + sc * 2) ^ ((sr0 & 7) << 4))) = kn0;
      *reinterpret_cast<uint4*>((char*)Ks[nb_] + ((sr1 * 128 + sc * 2) ^ ((sr1 & 7) << 4))) = kn1;
      *reinterpret_cast<uint4*>((char*)Vt[nb_] + ((sr0 * 128 + sc * 2) ^ ((sr0 & 7) << 4))) = vn0;
      *reinterpret_cast<uint4*>((char*)Vt[nb_] + ((sr1 * 128 + sc * 2) ^ ((sr1 & 7) << 4))) = vn1;
    }
    __syncthreads();
  }

  // ---- epilogue: O/l -> [tok][DMODEL] bf16 ----
  const int tok0 = b * SEQ + q0 + wave * 16 + g * 4;
#pragma unroll
  for (int r = 0; r < 4; ++r) {
    const float rinv = 1.0f / lrun[r];
#pragma unroll
    for (int ob = 0; ob < 4; ++ob)
      Og[(size_t)(tok0 + r) * DMODEL + h * 64 + ob * 16 + r16] = f2bf(o[ob][r] * rinv);
  }
}

// ---------------- launch ----------------
extern "C" void kernel_launch(void* const* d_in, const int* in_sizes, int n_in,
                              void* d_out, int out_size, void* d_ws, size_t ws_size,
                              hipStream_t stream) {
  const float* x  = (const float*)d_in[0];
  const float* wq = (const float*)d_in[1];
  const float* wk = (const float*)d_in[2];
  const float* wv = (const float*)d_in[3];
  const float* wo = (const float*)d_in[4];

  const size_t SZ_TOK = (size_t)MTOK * DMODEL * 2;
  const size_t SZ_W   = (size_t)DMODEL * DMODEL * 2;
  char* ws = (char*)d_ws;
  size_t off = 0;
  u16* xb  = (u16*)(ws + off); off += SZ_TOK;
  u16* wqb = (u16*)(ws + off); off += 4 * SZ_W;   // wq,wk,wv,wo contiguous
  u16* Qw  = (u16*)(ws + off); off += SZ_TOK;
  u16* Kw  = (u16*)(ws + off); off += SZ_TOK;
  u16* Vtw = (u16*)(ws + off); off += SZ_TOK;     // [B,H,DK,S]
  u16* Ow  = (u16*)(ws + off); off += SZ_TOK;
  if (ws_size < off) return;
  u16* wob = wqb + 3 * (size_t)DMODEL * DMODEL;

  const int nx4 = MTOK * DMODEL / 4;
  const int nw4 = DMODEL * DMODEL / 4;
  cvt_kernel<<<nx4 / 256, 256, 0, stream>>>(x, xb, nx4);
  cvt_w4<<<dim3(nw4 / 256, 4), 256, 0, stream>>>(wq, wk, wv, wo, wqb, nw4);

  qkv_gemm<<<dim3(MTOK / BM, DMODEL / BN, 3), 512, 0, stream>>>(xb, wqb, Qw, Kw, Vtw);

  attn_kernel<<<dim3(1536), 256, 0, stream>>>(Qw, Kw, Vtw, Ow);

  out_gemm<<<dim3(MTOK / BM, DMODEL / BN), 512, 0, stream>>>(Ow, wob, (float*)d_out);
}

// Round 5
// 205.550 us; speedup vs baseline: 2.0053x; 1.1824x over previous
//
#include <hip/hip_runtime.h>
#include <stdint.h>

#define DMODEL 768
#define NHEADS 12
#define DK 64
#define BATCH 4
#define SEQ 2048
#define MTOK (BATCH*SEQ)   // 8192 tokens

typedef float f32x4 __attribute__((ext_vector_type(4)));
typedef float f32x16 __attribute__((ext_vector_type(16)));
typedef short bf16x8 __attribute__((ext_vector_type(8)));
typedef unsigned short u16;
typedef unsigned int u32;

__device__ __forceinline__ u16 f2bf(float f) {
  uint32_t u = __float_as_uint(f);
  u += 0x7FFFu + ((u >> 16) & 1u);   // RNE
  return (u16)(u >> 16);
}

// async global->LDS, 16B per lane; LDS dest is wave-uniform base + lane*16
#define GLDS16(g, l) __builtin_amdgcn_global_load_lds( \
    (const __attribute__((address_space(1))) unsigned int*)(g), \
    (__attribute__((address_space(3))) unsigned int*)(l), 16, 0, 0)

// ---------------- fp32 -> bf16 convert ----------------
__global__ void cvt_kernel(const float* __restrict__ src, u16* __restrict__ dst, int n4) {
  int i = blockIdx.x * blockDim.x + threadIdx.x;
  if (i >= n4) return;
  float4 v = reinterpret_cast<const float4*>(src)[i];
  ushort4 o;
  o.x = f2bf(v.x); o.y = f2bf(v.y); o.z = f2bf(v.z); o.w = f2bf(v.w);
  reinterpret_cast<ushort4*>(dst)[i] = o;
}

__global__ void cvt_w4(const float* __restrict__ w0, const float* __restrict__ w1,
                       const float* __restrict__ w2, const float* __restrict__ w3,
                       u16* __restrict__ dst, int n4) {
  int i = blockIdx.x * blockDim.x + threadIdx.x;
  if (i >= n4) return;
  const float* src = (blockIdx.y == 0) ? w0 : (blockIdx.y == 1) ? w1 : (blockIdx.y == 2) ? w2 : w3;
  float4 v = reinterpret_cast<const float4*>(src)[i];
  ushort4 o;
  o.x = f2bf(v.x); o.y = f2bf(v.y); o.z = f2bf(v.z); o.w = f2bf(v.w);
  reinterpret_cast<ushort4*>(dst + (size_t)blockIdx.y * DMODEL * DMODEL)[i] = o;
}

// ---------------- shared GEMM main loop (unchanged, verified R3) ----------------
#define BM 128
#define BN 128
#define BK 32

__device__ __forceinline__ void gemm_loop(const u16* __restrict__ A, const u16* __restrict__ W,
                                          int bm, int bn, int t, u16* As, u16* Ws,
                                          f32x4 (&acc)[2][4]) {
  const int lane = t & 63;
  const int wave = t >> 6;
  const int r16 = lane & 15, g = lane >> 4;
  const int wr = (wave >> 1) * 32;
  const int wc = (wave & 1) * 64;
  const int crow = t >> 2;
  const int cchunk = (t & 3) ^ ((t >> 3) & 3);
  const size_t aoff = (size_t)(bm + crow) * DMODEL + cchunk * 8;
  const size_t woff = (size_t)(bn + crow) * DMODEL + cchunk * 8;

  GLDS16(A + aoff, As + t * 8);
  GLDS16(W + woff, Ws + t * 8);
  __syncthreads();

  const int NK = DMODEL / BK;   // 24
  for (int kt = 0; kt < NK; ++kt) {
    const int cur = kt & 1;
    if (kt + 1 < NK) {
      GLDS16(A + aoff + (size_t)(kt + 1) * BK, As + (cur ^ 1) * 4096 + t * 8);
      GLDS16(W + woff + (size_t)(kt + 1) * BK, Ws + (cur ^ 1) * 4096 + t * 8);
    }
    bf16x8 af[2], bfr[4];
#pragma unroll
    for (int m = 0; m < 2; ++m) {
      const int row = wr + m * 16 + r16;
      af[m] = *reinterpret_cast<const bf16x8*>(&As[cur * 4096 + row * 32 + ((g ^ ((row >> 1) & 3)) * 8)]);
    }
#pragma unroll
    for (int n = 0; n < 4; ++n) {
      const int row = wc + n * 16 + r16;
      bfr[n] = *reinterpret_cast<const bf16x8*>(&Ws[cur * 4096 + row * 32 + ((g ^ ((row >> 1) & 3)) * 8)]);
    }
#pragma unroll
    for (int m = 0; m < 2; ++m)
#pragma unroll
      for (int n = 0; n < 4; ++n)
        acc[m][n] = __builtin_amdgcn_mfma_f32_16x16x32_bf16(af[m], bfr[n], acc[m][n], 0, 0, 0);
    __syncthreads();
  }
}

// Fused QKV projection: z=0 Q (pre-scaled by 0.125), z=1 K, z=2 V^T
__launch_bounds__(512)
__global__ void qkv_gemm(const u16* __restrict__ A, const u16* __restrict__ wAll,
                         u16* __restrict__ Qw, u16* __restrict__ Kw, u16* __restrict__ Vtw) {
  __shared__ __align__(16) u16 As[2 * BM * BK];
  __shared__ __align__(16) u16 Ws[2 * BN * BK];
  const int t = threadIdx.x;
  const int lane = t & 63, wave = t >> 6;
  const int r16 = lane & 15, g = lane >> 4;
  const int bm = blockIdx.x * BM, bn = blockIdx.y * BN;
  const int z = blockIdx.z;
  const u16* W = wAll + (size_t)z * DMODEL * DMODEL;
  const int wr = (wave >> 1) * 32, wc = (wave & 1) * 64;

  f32x4 acc[2][4] = {};
  gemm_loop(A, W, bm, bn, t, As, Ws, acc);

  if (z <= 1) {
    u16* Qo = (z == 0) ? Qw : Kw;
    const float scl = (z == 0) ? 0.125f : 1.0f;
#pragma unroll
    for (int m = 0; m < 2; ++m) {
      const int gi0 = bm + wr + m * 16 + g * 4;
#pragma unroll
      for (int n = 0; n < 4; ++n) {
        const int gj = bn + wc + n * 16 + r16;
        const int h = gj >> 6, dc = gj & 63;
#pragma unroll
        for (int r = 0; r < 4; ++r) {
          const int gi = gi0 + r;
          const int b_ = gi >> 11, s = gi & 2047;
          Qo[((size_t)((b_ * NHEADS + h) * SEQ + s) << 6) + dc] = f2bf(acc[m][n][r] * scl);
        }
      }
    }
  } else {
#pragma unroll
    for (int m = 0; m < 2; ++m) {
      const int gi0 = bm + wr + m * 16 + g * 4;
      const int b_ = gi0 >> 11, s0 = gi0 & 2047;
#pragma unroll
      for (int n = 0; n < 4; ++n) {
        const int gj = bn + wc + n * 16 + r16;
        const int h = gj >> 6, dc = gj & 63;
        ushort4 pk;
        pk.x = f2bf(acc[m][n][0]); pk.y = f2bf(acc[m][n][1]);
        pk.z = f2bf(acc[m][n][2]); pk.w = f2bf(acc[m][n][3]);
        *reinterpret_cast<ushort4*>(Vtw + ((size_t)((b_ * NHEADS + h) * DK + dc) * SEQ + s0)) = pk;
      }
    }
  }
}

// Output projection: fp32 out row-major [M][N]
__launch_bounds__(512)
__global__ void out_gemm(const u16* __restrict__ A, const u16* __restrict__ W,
                         float* __restrict__ C) {
  __shared__ __align__(16) u16 As[2 * BM * BK];
  __shared__ __align__(16) u16 Ws[2 * BN * BK];
  const int t = threadIdx.x;
  const int lane = t & 63, wave = t >> 6;
  const int r16 = lane & 15, g = lane >> 4;
  const int bm = blockIdx.x * BM, bn = blockIdx.y * BN;
  const int wr = (wave >> 1) * 32, wc = (wave & 1) * 64;

  f32x4 acc[2][4] = {};
  gemm_loop(A, W, bm, bn, t, As, Ws, acc);

#pragma unroll
  for (int m = 0; m < 2; ++m) {
    const int gi0 = bm + wr + m * 16 + g * 4;
#pragma unroll
    for (int n = 0; n < 4; ++n) {
      const int gj = bn + wc + n * 16 + r16;
#pragma unroll
      for (int r = 0; r < 4; ++r)
        C[(size_t)(gi0 + r) * DMODEL + gj] = acc[m][n][r];
    }
  }
}

// ---- P fragment assembly: 8 own f32 P-values -> bf16x8 PV B-operand frag ----
// Direction-unambiguous version: explicit partner exchange via __shfl_xor(,32).
// Required frag (ks-block), lane (l31, hi):  elem e -> P[kv = 16ks + 8hi + e][q=l31]
//   hi=0: [own(p0,p1), own(p2,p3), partner(p0,p1), partner(p2,p3)]
//   hi=1: [partner(p4,p5), partner(p6,p7), own(p4,p5), own(p6,p7)]
__device__ __forceinline__ bf16x8 mk_pa(int hi, float p0, float p1, float p2, float p3,
                                        float p4, float p5, float p6, float p7) {
  u32 w01, w23, w45, w67;
  asm("v_cvt_pk_bf16_f32 %0, %1, %2" : "=v"(w01) : "v"(p0), "v"(p1));
  asm("v_cvt_pk_bf16_f32 %0, %1, %2" : "=v"(w23) : "v"(p2), "v"(p3));
  asm("v_cvt_pk_bf16_f32 %0, %1, %2" : "=v"(w45) : "v"(p4), "v"(p5));
  asm("v_cvt_pk_bf16_f32 %0, %1, %2" : "=v"(w67) : "v"(p6), "v"(p7));
  const u32 pw01 = (u32)__shfl_xor((int)w01, 32);
  const u32 pw23 = (u32)__shfl_xor((int)w23, 32);
  const u32 pw45 = (u32)__shfl_xor((int)w45, 32);
  const u32 pw67 = (u32)__shfl_xor((int)w67, 32);
  union { u32 w[4]; bf16x8 v; } u;
  u.w[0] = hi ? pw45 : w01;
  u.w[1] = hi ? pw67 : w23;
  u.w[2] = hi ? w45  : pw01;
  u.w[3] = hi ? w67  : pw23;
  return u.v;
}

// ---------------- causal flash attention (swapped-QK 32x32 structure) ----------------
// 4 warps x 32 q-rows = 128 q/block; KV tiles of 64, 2-phase global_load_lds dbuf.
// T = mfma(K, Q): lane owns q=lane&31; pair (l, l^32) holds full 64-kv P row.
// O^T = mfma(V^T, P^T): output col = q -> per-lane scalar m/l, in-lane rescale.
__launch_bounds__(256, 2)
__global__ void attn_kernel(const u16* __restrict__ Qg, const u16* __restrict__ Kg,
                            const u16* __restrict__ Vtg, u16* __restrict__ Og) {
  __shared__ __align__(16) u16 Ks[2][64 * 64];
  __shared__ __align__(16) u16 Vs[2][64 * 64];
  const int t = threadIdx.x;
  const int lane = t & 63, warp = t >> 6;
  const int l31 = lane & 31, hi = lane >> 5;
  const int bx = blockIdx.x;            // 0..767
  const int qt = 15 - (bx / 48);        // LPT: heaviest q-blocks first
  const int hb = bx % 48;
  const int h = hb % NHEADS, b = hb / NHEADS;
  const int q0w = qt * 128 + warp * 32;
  const int nt = 2 * qt + 2;            // kv tiles this block needs
  const size_t bh = (size_t)(b * NHEADS + h);
  const u16* Qb = Qg + bh * SEQ * DK;
  const u16* Kb = Kg + bh * SEQ * DK;
  const u16* Vb = Vtg + bh * DK * SEQ;  // [d][s]

  // staging map: LDS byte bb -> tile row bb>>7, source col ((bb&127)^((row&7)<<4))>>1
  int srow[2], scol[2];
#pragma unroll
  for (int j = 0; j < 2; ++j) {
    const int bb = (t + j * 256) * 16;
    srow[j] = bb >> 7;
    scol[j] = ((bb & 127) ^ ((srow[j] & 7) << 4)) >> 1;
  }

  const int q = q0w + l31;              // this lane's q-row
  // Q as B-operand frags: lane needs Q[q][16*kk + 8*hi + e]
  bf16x8 qf[4];
#pragma unroll
  for (int kk = 0; kk < 4; ++kk)
    qf[kk] = *reinterpret_cast<const bf16x8*>(Qb + (size_t)q * DK + kk * 16 + hi * 8);

  f32x16 o0 = {}, o1 = {};              // O^T: d = crow(reg,hi) + 32*{0,1}
  float m = -__builtin_inff(), l = 0.f;
  const int hi4 = hi * 4;
  const int xr = (l31 & 7) << 4;        // read swizzle term (same for row and row+32)

  // prologue: stage tile 0 into buffer 0
#pragma unroll
  for (int j = 0; j < 2; ++j) {
    GLDS16(Kb + (size_t)srow[j] * DK + scol[j], &Ks[0][0] + (t + j * 256) * 8);
    GLDS16(Vb + (size_t)srow[j] * SEQ + scol[j], &Vs[0][0] + (t + j * 256) * 8);
  }
  __syncthreads();

  for (int i = 0; i < nt; ++i) {
    const int cur = i & 1;
    const int kv0 = i * 64;
    if (i + 1 < nt) {                   // issue next tile early (overlaps compute)
      const int nkv0 = kv0 + 64;
#pragma unroll
      for (int j = 0; j < 2; ++j) {
        GLDS16(Kb + (size_t)(nkv0 + srow[j]) * DK + scol[j], &Ks[cur ^ 1][0] + (t + j * 256) * 8);
        GLDS16(Vb + (size_t)srow[j] * SEQ + nkv0 + scol[j], &Vs[cur ^ 1][0] + (t + j * 256) * 8);
      }
    }

    if (kv0 <= q0w + 31) {              // warp-uniform active check
      // ---- T = K Q^T : T[kv][q], lane col q=l31, rows crow(reg,hi)+32*tile ----
      f32x16 t0 = {}, t1 = {};
      const char* Kc = (const char*)Ks[cur];
#pragma unroll
      for (int kk = 0; kk < 4; ++kk) {
        const int cb = kk * 32 + hi * 16;
        bf16x8 a0 = *reinterpret_cast<const bf16x8*>(Kc + ((l31 * 128 + cb) ^ xr));
        bf16x8 a1 = *reinterpret_cast<const bf16x8*>(Kc + (((l31 + 32) * 128 + cb) ^ xr));
        t0 = __builtin_amdgcn_mfma_f32_32x32x16_bf16(a0, qf[kk], t0, 0, 0, 0);
        t1 = __builtin_amdgcn_mfma_f32_32x32x16_bf16(a1, qf[kk], t1, 0, 0, 0);
      }

      // ---- causal mask (diag tiles only) ----
      if (kv0 + 63 > q0w) {
        const int qmh = (q - kv0) - hi4;
#pragma unroll
        for (int r = 0; r < 16; ++r) {
          const int kvc = (r & 3) + 8 * (r >> 2);
          if (kvc > qmh)      t0[r] = -__builtin_inff();
          if (kvc + 32 > qmh) t1[r] = -__builtin_inff();
        }
      }

      // ---- row max: in-reg tree + partner exchange ----
      float x0 = fmaxf(t0[0], t0[1]),  x1 = fmaxf(t0[2], t0[3]);
      float x2 = fmaxf(t0[4], t0[5]),  x3 = fmaxf(t0[6], t0[7]);
      float x4 = fmaxf(t0[8], t0[9]),  x5 = fmaxf(t0[10], t0[11]);
      float x6 = fmaxf(t0[12], t0[13]), x7 = fmaxf(t0[14], t0[15]);
      x0 = fmaxf(x0, x1); x2 = fmaxf(x2, x3); x4 = fmaxf(x4, x5); x6 = fmaxf(x6, x7);
      float y0 = fmaxf(t1[0], t1[1]),  y1 = fmaxf(t1[2], t1[3]);
      float y2 = fmaxf(t1[4], t1[5]),  y3 = fmaxf(t1[6], t1[7]);
      float y4 = fmaxf(t1[8], t1[9]),  y5 = fmaxf(t1[10], t1[11]);
      float y6 = fmaxf(t1[12], t1[13]), y7 = fmaxf(t1[14], t1[15]);
      y0 = fmaxf(y0, y1); y2 = fmaxf(y2, y3); y4 = fmaxf(y4, y5); y6 = fmaxf(y6, y7);
      float pm = fmaxf(fmaxf(fmaxf(x0, x2), fmaxf(x4, x6)),
                       fmaxf(fmaxf(y0, y2), fmaxf(y4, y6)));
      pm = fmaxf(pm, __shfl_xor(pm, 32));   // full-row max (both lane halves)

      if (pm > m) {                     // exact skip-rescale (T13, THR=0)
        const float corr = __expf(m - pm);
        l *= corr;
        o0 = o0 * corr;
        o1 = o1 * corr;
        m = pm;
      }

      // ---- exp + row sum ----
#pragma unroll
      for (int r = 0; r < 16; ++r) { t0[r] = __expf(t0[r] - m); }
#pragma unroll
      for (int r = 0; r < 16; ++r) { t1[r] = __expf(t1[r] - m); }
      float s0 = 0.f, s1 = 0.f, s2 = 0.f, s3 = 0.f;
#pragma unroll
      for (int r = 0; r < 4; ++r) {
        s0 += t0[r]; s1 += t0[4 + r]; s2 += t0[8 + r]; s3 += t0[12 + r];
        s0 += t1[r]; s1 += t1[4 + r]; s2 += t1[8 + r]; s3 += t1[12 + r];
      }
      float s = (s0 + s1) + (s2 + s3);
      l += s + __shfl_xor(s, 32);       // both halves' partial sums

      // ---- P -> bf16 PV fragments (in-register, partner via shfl) ----
      bf16x8 pa0 = mk_pa(hi, t0[0], t0[1], t0[2], t0[3], t0[4], t0[5], t0[6], t0[7]);
      bf16x8 pa1 = mk_pa(hi, t0[8], t0[9], t0[10], t0[11], t0[12], t0[13], t0[14], t0[15]);
      bf16x8 pa2 = mk_pa(hi, t1[0], t1[1], t1[2], t1[3], t1[4], t1[5], t1[6], t1[7]);
      bf16x8 pa3 = mk_pa(hi, t1[8], t1[9], t1[10], t1[11], t1[12], t1[13], t1[14], t1[15]);

      // ---- O^T += V^T P^T ----
      const char* Vc = (const char*)Vs[cur];
#pragma unroll
      for (int ks = 0; ks < 4; ++ks) {
        const int cb = ks * 32 + hi * 16;
        bf16x8 v0 = *reinterpret_cast<const bf16x8*>(Vc + ((l31 * 128 + cb) ^ xr));
        bf16x8 v1 = *reinterpret_cast<const bf16x8*>(Vc + (((l31 + 32) * 128 + cb) ^ xr));
        const bf16x8 pk = (ks == 0) ? pa0 : (ks == 1) ? pa1 : (ks == 2) ? pa2 : pa3;
        o0 = __builtin_amdgcn_mfma_f32_32x32x16_bf16(v0, pk, o0, 0, 0, 0);
        o1 = __builtin_amdgcn_mfma_f32_32x32x16_bf16(v1, pk, o1, 0, 0, 0);
      }
    }
    __syncthreads();                    // drains GLDS (vmcnt) + publishes buf^1
  }

  // ---- epilogue: O^T/l -> Og[tok][DMODEL] ----
  const float rinv = 1.0f / l;
  u16* orow = Og + (size_t)(b * SEQ + q) * DMODEL + h * 64;
#pragma unroll
  for (int j = 0; j < 4; ++j) {
    ushort4 pk;
    pk.x = f2bf(o0[4 * j + 0] * rinv); pk.y = f2bf(o0[4 * j + 1] * rinv);
    pk.z = f2bf(o0[4 * j + 2] * rinv); pk.w = f2bf(o0[4 * j + 3] * rinv);
    *reinterpret_cast<ushort4*>(orow + 8 * j + hi4) = pk;
  }
#pragma unroll
  for (int j = 0; j < 4; ++j) {
    ushort4 pk;
    pk.x = f2bf(o1[4 * j + 0] * rinv); pk.y = f2bf(o1[4 * j + 1] * rinv);
    pk.z = f2bf(o1[4 * j + 2] * rinv); pk.w = f2bf(o1[4 * j + 3] * rinv);
    *reinterpret_cast<ushort4*>(orow + 32 + 8 * j + hi4) = pk;
  }
}

// ---------------- launch ----------------
extern "C" void kernel_launch(void* const* d_in, const int* in_sizes, int n_in,
                              void* d_out, int out_size, void* d_ws, size_t ws_size,
                              hipStream_t stream) {
  const float* x  = (const float*)d_in[0];
  const float* wq = (const float*)d_in[1];
  const float* wk = (const float*)d_in[2];
  const float* wv = (const float*)d_in[3];
  const float* wo = (const float*)d_in[4];

  const size_t SZ_TOK = (size_t)MTOK * DMODEL * 2;
  const size_t SZ_W   = (size_t)DMODEL * DMODEL * 2;
  char* ws = (char*)d_ws;
  size_t off = 0;
  u16* xb  = (u16*)(ws + off); off += SZ_TOK;
  u16* wqb = (u16*)(ws + off); off += 4 * SZ_W;   // wq,wk,wv,wo contiguous
  u16* Qw  = (u16*)(ws + off); off += SZ_TOK;
  u16* Kw  = (u16*)(ws + off); off += SZ_TOK;
  u16* Vtw = (u16*)(ws + off); off += SZ_TOK;     // [B,H,DK,S]
  u16* Ow  = (u16*)(ws + off); off += SZ_TOK;
  if (ws_size < off) return;
  u16* wob = wqb + 3 * (size_t)DMODEL * DMODEL;

  const int nx4 = MTOK * DMODEL / 4;
  const int nw4 = DMODEL * DMODEL / 4;
  cvt_kernel<<<nx4 / 256, 256, 0, stream>>>(x, xb, nx4);
  cvt_w4<<<dim3(nw4 / 256, 4), 256, 0, stream>>>(wq, wk, wv, wo, wqb, nw4);

  qkv_gemm<<<dim3(MTOK / BM, DMODEL / BN, 3), 512, 0, stream>>>(xb, wqb, Qw, Kw, Vtw);

  attn_kernel<<<dim3(768), 256, 0, stream>>>(Qw, Kw, Vtw, Ow);

  out_gemm<<<dim3(MTOK / BM, DMODEL / BN), 512, 0, stream>>>(Ow, wob, (float*)d_out);
}